// Round 6
// baseline (529.217 us; speedup 1.0000x reference)
//
#include <hip/hip_runtime.h>

#define B_    256
#define N_    256
#define DIN   768
#define DOUT  300
#define DOUTP 320           // padded to 20*16
#define M_    (B_*N_)       // 65536
#define HP_ELEMS (M_*DOUT)  // 19660800
#define NEG_INF -9.0e15f

typedef _Float16 f16;
typedef __attribute__((ext_vector_type(8))) _Float16 f16x8;
typedef __attribute__((ext_vector_type(4))) _Float16 f16x4;
typedef __attribute__((ext_vector_type(4))) float    f32x4;

// ---- kernel 0: WtT[kt][n][slot] = f16(W[kt*32+p][n]), K-permuted ----------
// K-permutation (applied identically to A and B, so GEMM is unchanged):
// phys p<16: slot = (p>>2)*8 + (p&3); p>=16: slot = ((p-16)>>2)*8+4+((p-16)&3).
// This makes the A-fragment two full-cache-line float4 loads per lane.
__global__ __launch_bounds__(256) void prep_wt(const float* __restrict__ W,
                                               f16* __restrict__ WtT) {
    int idx = blockIdx.x * 256 + threadIdx.x;      // over DIN*DOUTP
    if (idx >= DIN * DOUTP) return;
    int k = idx / DOUTP, n = idx - k * DOUTP;
    float v = (n < DOUT) ? W[k * DOUT + n] : 0.0f;
    int p = k & 31;
    int slot = (p < 16) ? ((p >> 2) * 8 + (p & 3))
                        : (((p - 16) >> 2) * 8 + 4 + ((p - 16) & 3));
    WtT[(((size_t)(k >> 5) * DOUTP + n) << 5) + slot] = (f16)v;
}

// ---- kernel 1: Wh = h@W + pos; f partials; WhT2 ---------------------------
// ONE-WAVE workgroups: grid 4096 = 1024 row-strips (64 rows) x 4 col-groups
// (80 cols). Every resident wave is an independent pipeline phase (no
// intra-block lockstep). A: two full-line dwordx4 per row-tile per kt
// (K-permuted), 2-deep. B: 1KB-contiguous f16x8 frags from L2-resident
// K-permuted WtT, 3-deep. Zero LDS, zero barriers in the K-loop.
// XCD-chunk swizzle: the 4 col-groups of a strip share one XCD's L2.
__global__ __launch_bounds__(64) void gemm1(
    const float* __restrict__ h, const f16* __restrict__ WtT,
    const int* __restrict__ positions,
    const float* __restrict__ a_src, const float* __restrict__ a_dst,
    const float* __restrict__ pos_table,
    f16* __restrict__ WhT2, float* __restrict__ f_srcP, float* __restrict__ f_dstP)
{
    const int lane = threadIdx.x;
    const int quad = lane >> 4, c = lane & 15;

    // XCD-chunk swizzle (4096 % 8 == 0 -> bijective)
    const int d = blockIdx.x;
    const int work  = (d & 7) * 512 + (d >> 3);
    const int strip = work >> 2;
    const int cg    = work & 3;
    const int rowbase = strip * 64;
    const int colbase = cg * 80;

    // A base: h[rowbase + rt*16 + c][quad*4 ...]; k-permuted fragment =
    // float4 at kt*32 and kt*32+16 (each instruction covers 16 full lines).
    const float* a0 = h + (size_t)(rowbase + c) * DIN + quad * 4;
    const float* a1 = a0 + 16 * DIN;
    const float* a2 = a0 + 32 * DIN;
    const float* a3 = a0 + 48 * DIN;

    int boffs[5];
#pragma unroll
    for (int i = 0; i < 5; ++i) {
        int n = colbase + i * 16 + c;
        boffs[i] = (n << 5) + (quad << 3);
    }

    f32x4 acc[4][5];
#pragma unroll
    for (int rt = 0; rt < 4; ++rt)
#pragma unroll
        for (int i = 0; i < 5; ++i) acc[rt][i] = (f32x4){0.f, 0.f, 0.f, 0.f};

    float4 av[2][4][2];   // [buf][row-tile][half] — static after full unroll
    f16x8  bs[3][5];
    f16x8  af[4];

#define LOADA(KT, S) do {                                                      \
    av[S][0][0] = *(const float4*)(a0 + (KT) * 32);                            \
    av[S][0][1] = *(const float4*)(a0 + (KT) * 32 + 16);                       \
    av[S][1][0] = *(const float4*)(a1 + (KT) * 32);                            \
    av[S][1][1] = *(const float4*)(a1 + (KT) * 32 + 16);                       \
    av[S][2][0] = *(const float4*)(a2 + (KT) * 32);                            \
    av[S][2][1] = *(const float4*)(a2 + (KT) * 32 + 16);                       \
    av[S][3][0] = *(const float4*)(a3 + (KT) * 32);                            \
    av[S][3][1] = *(const float4*)(a3 + (KT) * 32 + 16);                       \
} while (0)

#define LOADB(KT, S) do {                                                      \
    const f16* p_ = WtT + (size_t)(KT) * (DOUTP * 32);                         \
    _Pragma("unroll")                                                          \
    for (int i_ = 0; i_ < 5; ++i_)                                             \
        bs[S][i_] = *(const f16x8*)(p_ + boffs[i_]);                           \
} while (0)

#define CVT(S) do {                                                            \
    _Pragma("unroll")                                                          \
    for (int rt_ = 0; rt_ < 4; ++rt_) {                                        \
        float4 u0 = av[S][rt_][0], u1 = av[S][rt_][1];                         \
        af[rt_] = (f16x8){(f16)u0.x, (f16)u0.y, (f16)u0.z, (f16)u0.w,          \
                          (f16)u1.x, (f16)u1.y, (f16)u1.z, (f16)u1.w};         \
    } } while (0)

#define COMP(S) do {                                                           \
    __builtin_amdgcn_s_setprio(1);                                             \
    _Pragma("unroll")                                                          \
    for (int rt_ = 0; rt_ < 4; ++rt_)                                          \
        _Pragma("unroll")                                                      \
        for (int i_ = 0; i_ < 5; ++i_)                                         \
            acc[rt_][i_] = __builtin_amdgcn_mfma_f32_16x16x32_f16(             \
                af[rt_], bs[S][i_], acc[rt_][i_], 0, 0, 0);                    \
    __builtin_amdgcn_s_setprio(0);                                             \
} while (0)

    LOADA(0, 0);
    LOADB(0, 0);
    LOADB(1, 1);
#pragma unroll
    for (int kt = 0; kt < 24; ++kt) {
        if (kt + 1 < 24) LOADA(kt + 1, (kt + 1) & 1);
        if (kt + 2 < 24) LOADB(kt + 2, (kt + 2) % 3);
        CVT(kt & 1);
        COMP(kt % 3);
    }
#undef COMP
#undef CVT
#undef LOADB
#undef LOADA

    // ---- epilogue (single wave): pos add, f partials, WhT2 store ----
    const int bidx = rowbase >> 8;
    const int ktb0 = (rowbase & 255) >> 5;

    int posr[4][4];
#pragma unroll
    for (int rt = 0; rt < 4; ++rt)
#pragma unroll
        for (int r = 0; r < 4; ++r)
            posr[rt][r] = positions[rowbase + rt * 16 + quad * 4 + r];

    float fs[4][4], fd[4][4];
#pragma unroll
    for (int rt = 0; rt < 4; ++rt)
#pragma unroll
        for (int r = 0; r < 4; ++r) { fs[rt][r] = 0.f; fd[rt][r] = 0.f; }

#pragma unroll
    for (int i = 0; i < 5; ++i) {
        int col = colbase + i * 16 + c;
        if (col < DOUT) {
            float as = a_src[col], ad = a_dst[col];
#pragma unroll
            for (int rt = 0; rt < 4; ++rt)
#pragma unroll
                for (int r = 0; r < 4; ++r) {
                    float v = acc[rt][i][r] + pos_table[posr[rt][r] * DOUT + col];
                    acc[rt][i][r] = v;
                    fs[rt][r] += v * as;
                    fd[rt][r] += v * ad;
                }
        } else {
#pragma unroll
            for (int rt = 0; rt < 4; ++rt)
#pragma unroll
                for (int r = 0; r < 4; ++r) acc[rt][i][r] = 0.0f;
        }
    }
#pragma unroll
    for (int off = 1; off < 16; off <<= 1) {
#pragma unroll
        for (int rt = 0; rt < 4; ++rt)
#pragma unroll
            for (int r = 0; r < 4; ++r) {
                fs[rt][r] += __shfl_xor(fs[rt][r], off, 16);
                fd[rt][r] += __shfl_xor(fd[rt][r], off, 16);
            }
    }
    if (c == 0) {
#pragma unroll
        for (int rt = 0; rt < 4; ++rt)
#pragma unroll
            for (int r = 0; r < 4; ++r) {
                int row = rowbase + rt * 16 + quad * 4 + r;
                f_srcP[(size_t)cg * M_ + row] = fs[rt][r];
                f_dstP[(size_t)cg * M_ + row] = fd[rt][r];
            }
    }
    // WhT2[bidx][kt][g][col][4] — full-line coalesced stores
#pragma unroll
    for (int i = 0; i < 5; ++i) {
        int col = colbase + i * 16 + c;
#pragma unroll
        for (int rt = 0; rt < 4; ++rt) {
            f16x4 u = (f16x4){(f16)acc[rt][i][0], (f16)acc[rt][i][1],
                              (f16)acc[rt][i][2], (f16)acc[rt][i][3]};
            size_t off = (((size_t)(bidx * 8 + ktb0 + (rt >> 1)) * 8
                           + (rt & 1) * 4 + quad) * DOUTP + col) * 4;
            *(f16x4*)(WhT2 + off) = u;
        }
    }
}

// ---- kernel 2: fused masked-softmax + h_prime = att @ Wh ------------------
// grid 1024 (64 rows/block), 256 threads. P in swizzled LDS; B fragments
// direct global->reg from WhT2, double-buffered; single barrier total.
__global__ __launch_bounds__(256, 3) void fused2(
    const float* __restrict__ adj, const float* __restrict__ f_srcP,
    const float* __restrict__ f_dstP, const f16* __restrict__ WhT2,
    float* __restrict__ att, float* __restrict__ hp)
{
    __shared__ f16 Pl[64 * 256];        // 32 KB, XOR-swizzled

    const int tid  = threadIdx.x;
    const int wave = tid >> 6, lane = tid & 63;
    const int quad = lane >> 4, c = lane & 15;
    const int rowbase = blockIdx.x * 64;
    const int bidx = rowbase >> 8;
    const int cx7 = c & 7;

    const f16* wbase = WhT2 + (size_t)bidx * 8 * (DOUTP * 32);

    f16x8 bs[2][5];
#define PREF2(KT, S) do {                                                      \
    const f16* p_ = wbase + (size_t)(KT) * (DOUTP * 32);                       \
    _Pragma("unroll")                                                          \
    for (int i_ = 0; i_ < 5; ++i_) {                                           \
        int n_ = (wave * 5 + i_) * 16 + c;                                     \
        f16x4 lo_ = *(const f16x4*)(p_ + (2 * quad) * (DOUTP * 4) + n_ * 4);   \
        f16x4 hi_ = *(const f16x4*)(p_ + (2 * quad + 1) * (DOUTP * 4) + n_ * 4); \
        bs[S][i_] = (f16x8){lo_[0], lo_[1], lo_[2], lo_[3],                    \
                            hi_[0], hi_[1], hi_[2], hi_[3]};                   \
    } } while (0)

    // ---- phase 0: masked softmax for 64 rows; att out + P into LDS ----
    {
        float4 q0 = *(const float4*)(f_dstP + (size_t)bidx * N_ + lane * 4);
        float4 q1 = *(const float4*)(f_dstP + M_ + (size_t)bidx * N_ + lane * 4);
        float4 q2 = *(const float4*)(f_dstP + 2 * (size_t)M_ + (size_t)bidx * N_ + lane * 4);
        float4 q3 = *(const float4*)(f_dstP + 3 * (size_t)M_ + (size_t)bidx * N_ + lane * 4);
        float4 fd4 = make_float4(q0.x + q1.x + q2.x + q3.x,
                                 q0.y + q1.y + q2.y + q3.y,
                                 q0.z + q1.z + q2.z + q3.z,
                                 q0.w + q1.w + q2.w + q3.w);
        const float* arow = adj + (size_t)(rowbase + wave * 16) * N_ + lane * 4;
        float4 nx0 = *(const float4*)arow;
        float4 nx1 = *(const float4*)(arow + N_);
        for (int rr = 0; rr < 16; ++rr) {
            float4 a4 = nx0;
            nx0 = nx1;
            if (rr + 2 < 16) nx1 = *(const float4*)(arow + (size_t)(rr + 2) * N_);
            const int lrow = wave * 16 + rr;
            const int row  = rowbase + lrow;
            float fsv = f_srcP[row] + f_srcP[M_ + row]
                      + f_srcP[2 * (size_t)M_ + row] + f_srcP[3 * (size_t)M_ + row];

            float v, e0, e1, e2, e3;
            v = fsv + fd4.x; v = v >= 0.f ? v : 0.2f * v; e0 = a4.x > 0.f ? v : NEG_INF;
            v = fsv + fd4.y; v = v >= 0.f ? v : 0.2f * v; e1 = a4.y > 0.f ? v : NEG_INF;
            v = fsv + fd4.z; v = v >= 0.f ? v : 0.2f * v; e2 = a4.z > 0.f ? v : NEG_INF;
            v = fsv + fd4.w; v = v >= 0.f ? v : 0.2f * v; e3 = a4.w > 0.f ? v : NEG_INF;

            float mx = fmaxf(fmaxf(e0, e1), fmaxf(e2, e3));
#pragma unroll
            for (int off = 1; off < 64; off <<= 1) mx = fmaxf(mx, __shfl_xor(mx, off, 64));

            float p0 = __expf(e0 - mx), p1 = __expf(e1 - mx);
            float p2 = __expf(e2 - mx), p3 = __expf(e3 - mx);
            float s = p0 + p1 + p2 + p3;
#pragma unroll
            for (int off = 1; off < 64; off <<= 1) s += __shfl_xor(s, off, 64);

            float inv = 1.0f / s;
            *(float4*)(att + (size_t)row * N_ + lane * 4) =
                make_float4(p0 * inv, p1 * inv, p2 * inv, p3 * inv);
            int slot = (lane >> 1) ^ (lrow & 7);
            *(f16x4*)&Pl[lrow * 256 + slot * 8 + (lane & 1) * 4] =
                (f16x4){(f16)(p0 * inv), (f16)(p1 * inv), (f16)(p2 * inv), (f16)(p3 * inv)};
        }
    }
    PREF2(0, 0);
    __syncthreads();   // P visible — the only barrier

    // ---- phase 1: GEMM, A = P (LDS), B reg double-buffer, no barriers ----
    f32x4 acc[4][5];
#pragma unroll
    for (int rt = 0; rt < 4; ++rt)
#pragma unroll
        for (int i = 0; i < 5; ++i) acc[rt][i] = (f32x4){0.f, 0.f, 0.f, 0.f};

#define COMPUTE2(KT, S) do {                                                   \
    const int k4_ = (KT) * 4 + quad;                                           \
    __builtin_amdgcn_s_setprio(1);                                             \
    _Pragma("unroll")                                                          \
    for (int rt_ = 0; rt_ < 4; ++rt_) {                                        \
        f16x8 af = *(const f16x8*)&Pl[(rt_ * 16 + c) * 256 + ((k4_ ^ cx7) << 3)]; \
        _Pragma("unroll")                                                      \
        for (int i_ = 0; i_ < 5; ++i_)                                         \
            acc[rt_][i_] = __builtin_amdgcn_mfma_f32_16x16x32_f16(             \
                af, bs[S][i_], acc[rt_][i_], 0, 0, 0);                         \
    }                                                                          \
    __builtin_amdgcn_s_setprio(0);                                             \
    } while (0)

#pragma unroll
    for (int kt2 = 0; kt2 < 4; ++kt2) {
        const int ktA = 2 * kt2, ktB = 2 * kt2 + 1;
        PREF2(ktB, 1);
        COMPUTE2(ktA, 0);
        if (ktB + 1 < 8) PREF2(ktB + 1, 0);
        COMPUTE2(ktB, 1);
    }
#undef COMPUTE2
#undef PREF2

    // epilogue: hp[row][col], col<300
#pragma unroll
    for (int i = 0; i < 5; ++i) {
        int col = (wave * 5 + i) * 16 + c;
        if (col < DOUT) {
#pragma unroll
            for (int rt = 0; rt < 4; ++rt) {
                int row0 = rowbase + rt * 16 + quad * 4;
#pragma unroll
                for (int r = 0; r < 4; ++r)
                    hp[(size_t)(row0 + r) * DOUT + col] = acc[rt][i][r];
            }
        }
    }
}

extern "C" void kernel_launch(void* const* d_in, const int* in_sizes, int n_in,
                              void* d_out, int out_size, void* d_ws, size_t ws_size,
                              hipStream_t stream)
{
    const float* h         = (const float*)d_in[0];
    const float* adj       = (const float*)d_in[1];
    const int*   positions = (const int*)d_in[2];
    const float* W         = (const float*)d_in[3];
    const float* a_src     = (const float*)d_in[4];
    const float* a_dst     = (const float*)d_in[5];
    const float* pos_table = (const float*)d_in[6];

    float* hp  = (float*)d_out;            // [65536][300]
    float* att = hp + HP_ELEMS;            // [65536][256]

    f16*   WtT    = (f16*)d_ws;                        // [24][320][32] K-permuted
    f16*   WhT2   = WtT + (size_t)DOUTP * DIN;         // [256][8][8][320][4]
    float* f_srcP = (float*)(WhT2 + (size_t)B_ * DOUTP * N_);   // [4][65536]
    float* f_dstP = f_srcP + 4 * (size_t)M_;                    // [4][65536]

    hipLaunchKernelGGL(prep_wt, dim3((DIN * DOUTP + 255) / 256), dim3(256), 0, stream, W, WtT);
    hipLaunchKernelGGL(gemm1,   dim3(4096), dim3(64), 0, stream,
                       h, WtT, positions, a_src, a_dst, pos_table, WhT2, f_srcP, f_dstP);
    hipLaunchKernelGGL(fused2,  dim3(M_ / 64), dim3(256), 0, stream,
                       adj, f_srcP, f_dstP, WhT2, att, hp);
}

// Round 7
// 489.928 us; speedup vs baseline: 1.0802x; 1.0802x over previous
//
#include <hip/hip_runtime.h>

#define B_    256
#define N_    256
#define DIN   768
#define DOUT  300
#define DOUTP 320           // padded to 20*16
#define M_    (B_*N_)       // 65536
#define HP_ELEMS (M_*DOUT)  // 19660800
#define NEG_INF -9.0e15f

typedef _Float16 f16;
typedef __attribute__((ext_vector_type(8))) _Float16 f16x8;
typedef __attribute__((ext_vector_type(4))) _Float16 f16x4;
typedef __attribute__((ext_vector_type(4))) float    f32x4;

__device__ __forceinline__ void async_copy16(void* lds, const void* g) {
    __builtin_amdgcn_global_load_lds(
        (const __attribute__((address_space(1))) void*)g,
        (__attribute__((address_space(3))) void*)lds, 16, 0, 0);
}

// ---- kernel 0: WtT[kt][n][slot] = f16(W[k][n]), k-tiled, slot-swizzled ----
// slot = ((k>>3)&3) ^ ((n>>1)&3)  (so frag reads are ~2-way bank-free; DMA linear)
__global__ __launch_bounds__(256) void prep_wt(const float* __restrict__ W,
                                               f16* __restrict__ WtT) {
    int idx = blockIdx.x * 256 + threadIdx.x;      // over DIN*DOUTP
    if (idx >= DIN * DOUTP) return;
    int k = idx / DOUTP, n = idx - k * DOUTP;
    float v = (n < DOUT) ? W[k * DOUT + n] : 0.0f;
    int kt = k >> 5, sl = ((k >> 3) & 3) ^ ((n >> 1) & 3), e = k & 7;
    WtT[(((size_t)kt * DOUTP + n) << 5) + (sl << 3) + e] = (f16)v;
}

// ---- kernel 1: Wh = h@W + pos; f_src/f_dst; WhT2 ---------------------------
// grid 1024 strips of 64 rows, 256 threads (4 waves), 2 blocks/CU.
// Counted m201-style schedule, fully unrolled: B 3-deep in LDS (DMA),
// A 2-deep in regs; fixed issue stream [A(kt+2), B(kt+3)] pinned by
// sched_barrier(0); steady state 31 loads in flight, uniform vmcnt(18)
// per iteration (13 at kt=22, 0 at kt=23). Never drains.
__global__ __launch_bounds__(256, 2) void gemm1(
    const float* __restrict__ h, const f16* __restrict__ WtT,
    const int* __restrict__ positions,
    const float* __restrict__ a_src, const float* __restrict__ a_dst,
    const float* __restrict__ pos_table,
    f16* __restrict__ WhT2, float* __restrict__ f_src, float* __restrict__ f_dst)
{
    __shared__ f16 Bs[3][DOUTP * 32];   // 3 x 20 KB (DMA dst, linear)
    __shared__ float pfs[64][4], pfd[64][4];

    const int tid  = threadIdx.x;
    const int wave = tid >> 6, lane = tid & 63;
    const int quad = lane >> 4, c = lane & 15;
    const int rowbase = blockIdx.x * 64;

    // A: per-lane 8 consecutive f32 at k = kt*32 + quad*8 (two float4 each)
    const float* a0 = h + (size_t)(rowbase + c) * DIN + quad * 8;
    const float* a1 = a0 + 16 * DIN;
    const float* a2 = a0 + 32 * DIN;
    const float* a3 = a0 + 48 * DIN;

    int boffs[5];
#pragma unroll
    for (int i = 0; i < 5; ++i) {
        int n = (wave * 5 + i) * 16 + c;
        boffs[i] = (n << 5) + ((quad ^ ((n >> 1) & 3)) << 3);
    }

    f32x4 acc[4][5];
#pragma unroll
    for (int rt = 0; rt < 4; ++rt)
#pragma unroll
        for (int i = 0; i < 5; ++i) acc[rt][i] = (f32x4){0.f, 0.f, 0.f, 0.f};

    float4 av[2][4][2];   // A reg sets, depth 2 — static indices only
    f16x8  af[4];

#define STAGEB(KT, BUF) do {                                                   \
    _Pragma("unroll")                                                          \
    for (int i_ = 0; i_ < 5; ++i_) {                                           \
        int chk_ = wave * 5 + i_;                                              \
        async_copy16((char*)Bs[BUF] + chk_ * 1024,                             \
                     (const char*)WtT + (size_t)(KT) * 20480 + chk_ * 1024     \
                                      + lane * 16);                            \
    } } while (0)

#define LOADA(KT, S) do {                                                      \
    av[S][0][0] = *(const float4*)(a0 + (KT) * 32);                            \
    av[S][0][1] = *(const float4*)(a0 + (KT) * 32 + 4);                        \
    av[S][1][0] = *(const float4*)(a1 + (KT) * 32);                            \
    av[S][1][1] = *(const float4*)(a1 + (KT) * 32 + 4);                        \
    av[S][2][0] = *(const float4*)(a2 + (KT) * 32);                            \
    av[S][2][1] = *(const float4*)(a2 + (KT) * 32 + 4);                        \
    av[S][3][0] = *(const float4*)(a3 + (KT) * 32);                            \
    av[S][3][1] = *(const float4*)(a3 + (KT) * 32 + 4);                        \
} while (0)

#define CVT(S) do {                                                            \
    _Pragma("unroll")                                                          \
    for (int rt_ = 0; rt_ < 4; ++rt_) {                                        \
        float4 u0 = av[S][rt_][0], u1 = av[S][rt_][1];                         \
        af[rt_] = (f16x8){(f16)u0.x, (f16)u0.y, (f16)u0.z, (f16)u0.w,          \
                          (f16)u1.x, (f16)u1.y, (f16)u1.z, (f16)u1.w};         \
    } } while (0)

// ITER: SA=KT&1 (A set), SB=KT%3 (B buf); PA/PB: prefetch valid; VM: vmcnt literal
#define ITER(KT, SA, SB, PA, PB, VM) do {                                      \
    asm volatile("s_waitcnt vmcnt(" #VM ")");                                  \
    __builtin_amdgcn_sched_barrier(0);                                         \
    __builtin_amdgcn_s_barrier();                                              \
    __builtin_amdgcn_sched_barrier(0);                                         \
    CVT(SA);                                                                   \
    __builtin_amdgcn_s_setprio(1);                                             \
    _Pragma("unroll")                                                          \
    for (int i_ = 0; i_ < 5; ++i_) {                                           \
        f16x8 bf = *(const f16x8*)&Bs[SB][boffs[i_]];                          \
        acc[0][i_] = __builtin_amdgcn_mfma_f32_16x16x32_f16(af[0], bf, acc[0][i_], 0, 0, 0); \
        acc[1][i_] = __builtin_amdgcn_mfma_f32_16x16x32_f16(af[1], bf, acc[1][i_], 0, 0, 0); \
        acc[2][i_] = __builtin_amdgcn_mfma_f32_16x16x32_f16(af[2], bf, acc[2][i_], 0, 0, 0); \
        acc[3][i_] = __builtin_amdgcn_mfma_f32_16x16x32_f16(af[3], bf, acc[3][i_], 0, 0, 0); \
    }                                                                          \
    __builtin_amdgcn_s_setprio(0);                                             \
    __builtin_amdgcn_sched_barrier(0);                                         \
    __builtin_amdgcn_s_barrier();                                              \
    __builtin_amdgcn_sched_barrier(0);                                         \
    if (PA) { LOADA((KT) + 2, SA); }                                           \
    __builtin_amdgcn_sched_barrier(0);                                         \
    if (PB) { STAGEB((KT) + 3, SB); }                                          \
    __builtin_amdgcn_sched_barrier(0);                                         \
} while (0)

    // ---- prologue: pinned issue order [A0,B0,A1,B1,B2] = 31 outstanding ----
    LOADA(0, 0);  __builtin_amdgcn_sched_barrier(0);
    STAGEB(0, 0); __builtin_amdgcn_sched_barrier(0);
    LOADA(1, 1);  __builtin_amdgcn_sched_barrier(0);
    STAGEB(1, 1); __builtin_amdgcn_sched_barrier(0);
    STAGEB(2, 2); __builtin_amdgcn_sched_barrier(0);

    ITER( 0, 0, 0, 1, 1, 18);
    ITER( 1, 1, 1, 1, 1, 18);
    ITER( 2, 0, 2, 1, 1, 18);
    ITER( 3, 1, 0, 1, 1, 18);
    ITER( 4, 0, 1, 1, 1, 18);
    ITER( 5, 1, 2, 1, 1, 18);
    ITER( 6, 0, 0, 1, 1, 18);
    ITER( 7, 1, 1, 1, 1, 18);
    ITER( 8, 0, 2, 1, 1, 18);
    ITER( 9, 1, 0, 1, 1, 18);
    ITER(10, 0, 1, 1, 1, 18);
    ITER(11, 1, 2, 1, 1, 18);
    ITER(12, 0, 0, 1, 1, 18);
    ITER(13, 1, 1, 1, 1, 18);
    ITER(14, 0, 2, 1, 1, 18);
    ITER(15, 1, 0, 1, 1, 18);
    ITER(16, 0, 1, 1, 1, 18);
    ITER(17, 1, 2, 1, 1, 18);
    ITER(18, 0, 0, 1, 1, 18);
    ITER(19, 1, 1, 1, 1, 18);
    ITER(20, 0, 2, 1, 1, 18);   // last B issue (B23)
    ITER(21, 1, 0, 1, 0, 18);   // last A issue (A23)
    ITER(22, 0, 1, 0, 0, 13);
    ITER(23, 1, 2, 0, 0,  0);

#undef ITER
#undef CVT
#undef LOADA
#undef STAGEB

    // ---- epilogue: pos add, f_src/f_dst, WhT2 store (full-line layout) ----
    const int bidx = rowbase >> 8;
    const int ktb0 = (rowbase & 255) >> 5;       // 64 rows span 2 k-tiles

    int posr[4][4];
#pragma unroll
    for (int rt = 0; rt < 4; ++rt)
#pragma unroll
        for (int r = 0; r < 4; ++r)
            posr[rt][r] = positions[rowbase + rt * 16 + quad * 4 + r];

    float fs[4][4], fd[4][4];
#pragma unroll
    for (int rt = 0; rt < 4; ++rt)
#pragma unroll
        for (int r = 0; r < 4; ++r) { fs[rt][r] = 0.f; fd[rt][r] = 0.f; }

#pragma unroll
    for (int i = 0; i < 5; ++i) {
        int col = (wave * 5 + i) * 16 + c;
        if (col < DOUT) {
            float as = a_src[col], ad = a_dst[col];
#pragma unroll
            for (int rt = 0; rt < 4; ++rt)
#pragma unroll
                for (int r = 0; r < 4; ++r) {
                    float v = acc[rt][i][r] + pos_table[posr[rt][r] * DOUT + col];
                    acc[rt][i][r] = v;
                    fs[rt][r] += v * as;
                    fd[rt][r] += v * ad;
                }
        } else {
#pragma unroll
            for (int rt = 0; rt < 4; ++rt)
#pragma unroll
                for (int r = 0; r < 4; ++r) acc[rt][i][r] = 0.0f;
        }
    }
#pragma unroll
    for (int off = 1; off < 16; off <<= 1) {
#pragma unroll
        for (int rt = 0; rt < 4; ++rt)
#pragma unroll
            for (int r = 0; r < 4; ++r) {
                fs[rt][r] += __shfl_xor(fs[rt][r], off, 16);
                fd[rt][r] += __shfl_xor(fd[rt][r], off, 16);
            }
    }
    if (c == 0) {
#pragma unroll
        for (int rt = 0; rt < 4; ++rt)
#pragma unroll
            for (int r = 0; r < 4; ++r) {
                int row = rt * 16 + quad * 4 + r;
                pfs[row][wave] = fs[rt][r];
                pfd[row][wave] = fd[rt][r];
            }
    }
    // WhT2[bidx][kt][g][col][4]: full-line coalesced stores
#pragma unroll
    for (int i = 0; i < 5; ++i) {
        int col = (wave * 5 + i) * 16 + c;
#pragma unroll
        for (int rt = 0; rt < 4; ++rt) {
            f16x4 u = (f16x4){(f16)acc[rt][i][0], (f16)acc[rt][i][1],
                              (f16)acc[rt][i][2], (f16)acc[rt][i][3]};
            size_t off = (((size_t)(bidx * 8 + ktb0 + (rt >> 1)) * 8
                           + (rt & 1) * 4 + quad) * DOUTP + col) * 4;
            *(f16x4*)(WhT2 + off) = u;
        }
    }
    __syncthreads();
    if (tid < 64) {
        f_src[rowbase + tid] = pfs[tid][0] + pfs[tid][1] + pfs[tid][2] + pfs[tid][3];
        f_dst[rowbase + tid] = pfd[tid][0] + pfd[tid][1] + pfd[tid][2] + pfd[tid][3];
    }
}

// ---- kernel 2: fused masked-softmax + h_prime = att @ Wh ------------------
// grid 1024 (64 rows/block), 256 threads. P in swizzled LDS; B fragments
// direct global->reg from WhT2 (two f16x4 per fragment), double-buffered;
// single barrier total. (r4-verified structure.)
__global__ __launch_bounds__(256, 3) void fused2(
    const float* __restrict__ adj, const float* __restrict__ f_src,
    const float* __restrict__ f_dst, const f16* __restrict__ WhT2,
    float* __restrict__ att, float* __restrict__ hp)
{
    __shared__ f16 Pl[64 * 256];        // 32 KB, XOR-swizzled

    const int tid  = threadIdx.x;
    const int wave = tid >> 6, lane = tid & 63;
    const int quad = lane >> 4, c = lane & 15;
    const int rowbase = blockIdx.x * 64;
    const int bidx = rowbase >> 8;
    const int cx7 = c & 7;

    const f16* wbase = WhT2 + (size_t)bidx * 8 * (DOUTP * 32);

    f16x8 bs[2][5];
#define PREF2(KT, S) do {                                                      \
    const f16* p_ = wbase + (size_t)(KT) * (DOUTP * 32);                       \
    _Pragma("unroll")                                                          \
    for (int i_ = 0; i_ < 5; ++i_) {                                           \
        int n_ = (wave * 5 + i_) * 16 + c;                                     \
        f16x4 lo_ = *(const f16x4*)(p_ + (2 * quad) * (DOUTP * 4) + n_ * 4);   \
        f16x4 hi_ = *(const f16x4*)(p_ + (2 * quad + 1) * (DOUTP * 4) + n_ * 4); \
        bs[S][i_] = (f16x8){lo_[0], lo_[1], lo_[2], lo_[3],                    \
                            hi_[0], hi_[1], hi_[2], hi_[3]};                   \
    } } while (0)

    // ---- phase 0: masked softmax for 64 rows; att out + P into LDS ----
    {
        float4 fd4 = *(const float4*)(f_dst + bidx * N_ + lane * 4);
        const float* arow = adj + (size_t)(rowbase + wave * 16) * N_ + lane * 4;
        float4 nx0 = *(const float4*)arow;
        float4 nx1 = *(const float4*)(arow + N_);
        for (int rr = 0; rr < 16; ++rr) {
            float4 a4 = nx0;
            nx0 = nx1;
            if (rr + 2 < 16) nx1 = *(const float4*)(arow + (size_t)(rr + 2) * N_);
            const int lrow = wave * 16 + rr;
            const int row  = rowbase + lrow;
            float fsv = f_src[row];

            float v, e0, e1, e2, e3;
            v = fsv + fd4.x; v = v >= 0.f ? v : 0.2f * v; e0 = a4.x > 0.f ? v : NEG_INF;
            v = fsv + fd4.y; v = v >= 0.f ? v : 0.2f * v; e1 = a4.y > 0.f ? v : NEG_INF;
            v = fsv + fd4.z; v = v >= 0.f ? v : 0.2f * v; e2 = a4.z > 0.f ? v : NEG_INF;
            v = fsv + fd4.w; v = v >= 0.f ? v : 0.2f * v; e3 = a4.w > 0.f ? v : NEG_INF;

            float mx = fmaxf(fmaxf(e0, e1), fmaxf(e2, e3));
#pragma unroll
            for (int off = 1; off < 64; off <<= 1) mx = fmaxf(mx, __shfl_xor(mx, off, 64));

            float p0 = __expf(e0 - mx), p1 = __expf(e1 - mx);
            float p2 = __expf(e2 - mx), p3 = __expf(e3 - mx);
            float s = p0 + p1 + p2 + p3;
#pragma unroll
            for (int off = 1; off < 64; off <<= 1) s += __shfl_xor(s, off, 64);

            float inv = 1.0f / s;
            *(float4*)(att + (size_t)row * N_ + lane * 4) =
                make_float4(p0 * inv, p1 * inv, p2 * inv, p3 * inv);
            int slot = (lane >> 1) ^ (lrow & 7);
            *(f16x4*)&Pl[lrow * 256 + slot * 8 + (lane & 1) * 4] =
                (f16x4){(f16)(p0 * inv), (f16)(p1 * inv), (f16)(p2 * inv), (f16)(p3 * inv)};
        }
    }
    PREF2(0, 0);
    __syncthreads();   // P visible — the only barrier

    // ---- phase 1: GEMM, A = P (LDS), B reg double-buffer, no barriers ----
    f32x4 acc[4][5];
#pragma unroll
    for (int rt = 0; rt < 4; ++rt)
#pragma unroll
        for (int i = 0; i < 5; ++i) acc[rt][i] = (f32x4){0.f, 0.f, 0.f, 0.f};

#define COMPUTE2(KT, S) do {                                                   \
    const int k4_ = (KT) * 4 + quad;                                           \
    __builtin_amdgcn_s_setprio(1);                                             \
    _Pragma("unroll")                                                          \
    for (int rt_ = 0; rt_ < 4; ++rt_) {                                        \
        f16x8 af = *(const f16x8*)&Pl[(rt_ * 16 + c) * 256 + ((k4_ ^ cx7) << 3)]; \
        _Pragma("unroll")                                                      \
        for (int i_ = 0; i_ < 5; ++i_)                                         \
            acc[rt_][i_] = __builtin_amdgcn_mfma_f32_16x16x32_f16(             \
                af, bs[S][i_], acc[rt_][i_], 0, 0, 0);                         \
    }                                                                          \
    __builtin_amdgcn_s_setprio(0);                                             \
    } while (0)

#pragma unroll
    for (int kt2 = 0; kt2 < 4; ++kt2) {
        const int ktA = 2 * kt2, ktB = 2 * kt2 + 1;
        PREF2(ktB, 1);
        COMPUTE2(ktA, 0);
        if (ktB + 1 < 8) PREF2(ktB + 1, 0);
        COMPUTE2(ktB, 1);
    }
#undef COMPUTE2
#undef PREF2

    // epilogue: hp[row][col], col<300
#pragma unroll
    for (int i = 0; i < 5; ++i) {
        int col = (wave * 5 + i) * 16 + c;
        if (col < DOUT) {
#pragma unroll
            for (int rt = 0; rt < 4; ++rt) {
                int row0 = rowbase + rt * 16 + quad * 4;
#pragma unroll
                for (int r = 0; r < 4; ++r)
                    hp[(size_t)(row0 + r) * DOUT + col] = acc[rt][i][r];
            }
        }
    }
}

extern "C" void kernel_launch(void* const* d_in, const int* in_sizes, int n_in,
                              void* d_out, int out_size, void* d_ws, size_t ws_size,
                              hipStream_t stream)
{
    const float* h         = (const float*)d_in[0];
    const float* adj       = (const float*)d_in[1];
    const int*   positions = (const int*)d_in[2];
    const float* W         = (const float*)d_in[3];
    const float* a_src     = (const float*)d_in[4];
    const float* a_dst     = (const float*)d_in[5];
    const float* pos_table = (const float*)d_in[6];

    float* hp  = (float*)d_out;            // [65536][300]
    float* att = hp + HP_ELEMS;            // [65536][256]

    f16*   WtT   = (f16*)d_ws;                         // [24][320][32] swizzled
    f16*   WhT2  = WtT + (size_t)DOUTP * DIN;          // [256][8][8][320][4]
    float* f_src = (float*)(WhT2 + (size_t)B_ * DOUTP * N_);
    float* f_dst = f_src + M_;

    hipLaunchKernelGGL(prep_wt, dim3((DIN * DOUTP + 255) / 256), dim3(256), 0, stream, W, WtT);
    hipLaunchKernelGGL(gemm1,   dim3(M_ / 64), dim3(256), 0, stream,
                       h, WtT, positions, a_src, a_dst, pos_table, WhT2, f_src, f_dst);
    hipLaunchKernelGGL(fused2,  dim3(M_ / 64), dim3(256), 0, stream,
                       adj, f_src, f_dst, WhT2, att, hp);
}